// Round 1
// baseline (1289.098 us; speedup 1.0000x reference)
//
#include <hip/hip_runtime.h>
#include <float.h>

#define K_CODES 1024

// ---------------------------------------------------------------------------
// |e|^2 per code: one wave per code, 4 codes per 256-thread block.
// ---------------------------------------------------------------------------
template<int D>
__global__ void ee_kernel(const float* __restrict__ emb, float* __restrict__ ee)
{
    const int w  = threadIdx.x >> 6;
    const int ln = threadIdx.x & 63;
    const int k  = blockIdx.x * 4 + w;
    float s = 0.f;
    for (int d = ln; d < D; d += 64) {
        float v = emb[k * D + d];
        s = fmaf(v, v, s);
    }
#pragma unroll
    for (int m = 32; m >= 1; m >>= 1) s += __shfl_xor(s, m);
    if (ln == 0) ee[k] = s;
}

// ---------------------------------------------------------------------------
// Main VQ kernel: 64 points x 1024 codes per workgroup, fp32 register-tiled.
// dist(n,k) = |e_k|^2 - 2 x_n.e_k   (|x|^2 dropped: constant per point)
// Thread grid 8(pt-octets) x 32(code-octets); acc tile 8x8; D chunked by 32.
// ---------------------------------------------------------------------------
template<int D, int HW>
__global__ __launch_bounds__(256, 2)
void vq_level_kernel(const float* __restrict__ x,
                     const float* __restrict__ emb,
                     const float* __restrict__ ee,
                     float* __restrict__ out_feat,
                     float* __restrict__ loss_out,
                     float loss_scale)
{
    constexpr int KD = 32;    // depth chunk
    constexpr int MP = 64;    // points per workgroup
    constexpr int NC = 256;   // codes per tile

    __shared__ float xs[KD][MP];       // [d][p]
    __shared__ float es[KD * NC];      // [d][swizzled c]
    __shared__ int   sidx[MP];

    const int tid = threadIdx.x;
    const int tx  = tid & 31;   // code octet: logical codes tx*8 .. tx*8+7
    const int ty  = tid >> 5;   // point octet: points ty*8 .. ty*8+7

    const int pt0 = blockIdx.x * MP;        // HW % 64 == 0 -> tile within one b
    const int b   = pt0 / HW;
    const int hw0 = pt0 % HW;
    const float* xbase = x + (b * D) * HW + hw0;

    float best[8];
    int   bidx[8];
#pragma unroll
    for (int i = 0; i < 8; ++i) { best[i] = FLT_MAX; bidx[i] = 0; }

    for (int ct = 0; ct < K_CODES / NC; ++ct) {
        float acc[8][8];
#pragma unroll
        for (int i = 0; i < 8; ++i)
#pragma unroll
            for (int j = 0; j < 8; ++j) acc[i][j] = 0.f;

        for (int dc = 0; dc < D / KD; ++dc) {
            __syncthreads();   // previous tile's LDS reads complete

            // ---- stage x chunk: [KD][MP], coalesced float4 along points ----
#pragma unroll
            for (int r = 0; r < 2; ++r) {
                int idx = r * 256 + tid;
                int p4  = idx & 15;        // float4 group along points
                int d   = idx >> 4;        // 0..31
                float4 v = *(const float4*)(xbase + (dc * KD + d) * HW + p4 * 4);
                *(float4*)&xs[d][p4 * 4] = v;
            }

            // ---- stage e chunk transposed w/ octet swizzle ----
            // thread: fixed d4 = tid&7 (4 consecutive d), codes c = 32r + tid/8
            // phys location of logical (d, c): d*NC + ((c>>3) ^ ((d>>2)&3))*8 + (c&7)
            {
                int d4 = tid & 7;
                int cb = tid >> 3;
#pragma unroll
                for (int r = 0; r < 8; ++r) {
                    int c = r * 32 + cb;
                    float4 v = *(const float4*)(emb + (ct * NC + c) * D + dc * KD + d4 * 4);
                    float vv[4] = {v.x, v.y, v.z, v.w};
                    int o = c >> 3, u = c & 7;
#pragma unroll
                    for (int j = 0; j < 4; ++j) {
                        int d  = d4 * 4 + j;
                        int po = o ^ ((d >> 2) & 3);
                        es[d * NC + po * 8 + u] = vv[j];
                    }
                }
            }
            __syncthreads();

            // ---- inner product accumulation ----
#pragma unroll 4
            for (int d = 0; d < KD; ++d) {
                float4 xa4 = *(const float4*)&xs[d][ty * 8];
                float4 xb4 = *(const float4*)&xs[d][ty * 8 + 4];
                int po = (tx ^ ((d >> 2) & 3)) << 3;
                float4 ea4 = *(const float4*)&es[d * NC + po];
                float4 eb4 = *(const float4*)&es[d * NC + po + 4];
                float xv[8] = {xa4.x, xa4.y, xa4.z, xa4.w, xb4.x, xb4.y, xb4.z, xb4.w};
                float ev[8] = {ea4.x, ea4.y, ea4.z, ea4.w, eb4.x, eb4.y, eb4.z, eb4.w};
#pragma unroll
                for (int i = 0; i < 8; ++i)
#pragma unroll
                    for (int j = 0; j < 8; ++j)
                        acc[i][j] = fmaf(xv[i], ev[j], acc[i][j]);
            }
        }

        // ---- fold this code tile into running argmin (codes ascending) ----
#pragma unroll
        for (int j = 0; j < 8; ++j) {
            int c = ct * NC + tx * 8 + j;
            float eec = ee[c];
#pragma unroll
            for (int i = 0; i < 8; ++i) {
                float dist = fmaf(-2.f, acc[i][j], eec);
                if (dist < best[i]) { best[i] = dist; bidx[i] = c; }
            }
        }
    }

    // ---- cross-lane argmin over the 32 code-octet threads (same wave) ----
#pragma unroll
    for (int i = 0; i < 8; ++i) {
        float v = best[i];
        int   ix = bidx[i];
#pragma unroll
        for (int m = 16; m >= 1; m >>= 1) {
            float v2 = __shfl_xor(v, m);
            int   i2 = __shfl_xor(ix, m);
            if (v2 < v || (v2 == v && i2 < ix)) { v = v2; ix = i2; }
        }
        if (tx == 0) sidx[ty * 8 + i] = ix;
    }
    __syncthreads();

    // ---- gather codes, write NCHW features (coalesced), commitment loss ----
    float lsum = 0.f;
#pragma unroll 4
    for (int r = 0; r < D / 4; ++r) {
        int idx = r * 256 + tid;
        int p   = idx & 63;    // consecutive lanes -> consecutive points
        int dd  = idx >> 6;
        int k   = sidx[p];
        float e    = emb[k * D + dd];           // scattered, L2-hot
        float xv   = xbase[dd * HW + p];        // coalesced
        float diff = e - xv;
        lsum = fmaf(diff, diff, lsum);
        out_feat[(b * D + dd) * HW + hw0 + p] = e;   // coalesced
    }
#pragma unroll
    for (int m = 32; m >= 1; m >>= 1) lsum += __shfl_xor(lsum, m);
    if ((tid & 63) == 0) atomicAdd(loss_out, lsum * loss_scale);
}

// ---------------------------------------------------------------------------
extern "C" void kernel_launch(void* const* d_in, const int* in_sizes, int n_in,
                              void* d_out, int out_size, void* d_ws, size_t ws_size,
                              hipStream_t stream)
{
    const float* x0 = (const float*)d_in[0];
    const float* e0 = (const float*)d_in[1];
    const float* x1 = (const float*)d_in[2];
    const float* e1 = (const float*)d_in[3];
    const float* x2 = (const float*)d_in[4];
    const float* e2 = (const float*)d_in[5];

    float* out  = (float*)d_out;
    float* loss = out;                          // out[0]
    float* f0   = out + 1;
    float* f1   = f0 + 8 * 64 * 96 * 320;       // 15728640
    float* f2   = f1 + 8 * 128 * 48 * 160;      // 7864320

    float* ee = (float*)d_ws;                   // 3*1024 floats of scratch

    hipMemsetAsync(loss, 0, sizeof(float), stream);

    ee_kernel<64 ><<<256, 256, 0, stream>>>(e0, ee);
    ee_kernel<128><<<256, 256, 0, stream>>>(e1, ee + 1024);
    ee_kernel<256><<<256, 256, 0, stream>>>(e2, ee + 2048);

    // N/64 workgroups per level
    vq_level_kernel<64,  96 * 320><<<3840, 256, 0, stream>>>(
        x0, e0, ee,        f0, loss, 0.25f / (245760.f * 64.f));
    vq_level_kernel<128, 48 * 160><<< 960, 256, 0, stream>>>(
        x1, e1, ee + 1024, f1, loss, 0.25f / (61440.f * 128.f));
    vq_level_kernel<256, 24 * 80 ><<< 240, 256, 0, stream>>>(
        x2, e2, ee + 2048, f2, loss, 0.25f / (15360.f * 256.f));
}

// Round 2
// 955.528 us; speedup vs baseline: 1.3491x; 1.3491x over previous
//
#include <hip/hip_runtime.h>
#include <float.h>

constexpr int KD = 32;    // depth chunk
constexpr int MP = 64;    // points per block
constexpr int NC = 256;   // codes per LDS tile

// ---------------------------------------------------------------------------
// |e|^2 per code: one wave per code, 4 codes per 256-thread block.
// ---------------------------------------------------------------------------
template<int D>
__global__ void ee_kernel(const float* __restrict__ emb, float* __restrict__ ee)
{
    const int w  = threadIdx.x >> 6;
    const int ln = threadIdx.x & 63;
    const int k  = blockIdx.x * 4 + w;
    float s = 0.f;
    for (int d = ln; d < D; d += 64) {
        float v = emb[(size_t)k * D + d];
        s = fmaf(v, v, s);
    }
#pragma unroll
    for (int m = 32; m >= 1; m >>= 1) s += __shfl_xor(s, m);
    if (ln == 0) ee[k] = s;
}

// ---------------------------------------------------------------------------
// Core VQ block: 64 points x KS codes, fp32 8x8 register tile.
// es LDS layout (conflict-free): logical (d, c) stored at
//   es[d*NC + (((c>>2) ^ (d>>2)) << 2) + (c&3)]
// Read: lane tx takes codes {tx*4+j} and {128+tx*4+j}; granules tx^f and
// 32+(tx^f) are consecutive across lanes -> all bank quads covered (0-conflict).
// Write: 2 lanes/bank (free).
// ---------------------------------------------------------------------------
template<int D, int HW, int KS>
__device__ __forceinline__
void vq_block(const float* __restrict__ x, const float* __restrict__ emb,
              const float* __restrict__ ee,
              float* __restrict__ out_feat, float* __restrict__ loss_out,
              float loss_scale,
              float* __restrict__ pdist, int* __restrict__ pidx, int Npts,
              int pt_blk, int split, char* smem)
{
    float* xs   = (float*)smem;            // [KD][MP]
    float* es   = xs + KD * MP;            // [KD][NC] swizzled
    int*   sidx = (int*)(es + KD * NC);    // [MP]

    const int tid = threadIdx.x;
    const int tx  = tid & 31;
    const int ty  = tid >> 5;
    const int f   = tid & 7;               // float4-along-D index for staging
    const int cb  = tid >> 3;

    const int pt0 = pt_blk * MP;           // HW % 64 == 0 -> tile within one b
    const int b   = pt0 / HW;
    const int hw0 = pt0 % HW;
    const float* xbase = x + (size_t)b * D * HW + hw0;

    float best[8]; int bidx[8];
#pragma unroll
    for (int i = 0; i < 8; ++i) { best[i] = FLT_MAX; bidx[i] = 0; }

    for (int ct = 0; ct < KS / NC; ++ct) {
        const int k0 = split * KS + ct * NC;
        float acc[8][8];
#pragma unroll
        for (int i = 0; i < 8; ++i)
#pragma unroll
            for (int j = 0; j < 8; ++j) acc[i][j] = 0.f;

        for (int dc = 0; dc < D / KD; ++dc) {
            __syncthreads();   // previous chunk's LDS reads complete

            // ---- stage x chunk: [KD][MP], float4 along points ----
#pragma unroll
            for (int r = 0; r < 2; ++r) {
                int idx = r * 256 + tid;
                int p4  = idx & 15;
                int d   = idx >> 4;
                float4 v = *(const float4*)(xbase + (size_t)(dc * KD + d) * HW + p4 * 4);
                *(float4*)&xs[d * MP + p4 * 4] = v;
            }

            // ---- stage e chunk, transposed + XOR-f swizzle ----
#pragma unroll
            for (int r = 0; r < 8; ++r) {
                int c = r * 32 + cb;
                float4 v = *(const float4*)(emb + (size_t)(k0 + c) * D + dc * KD + f * 4);
                int gc = (((c >> 2) ^ f) << 2) + (c & 3);
                es[(f * 4 + 0) * NC + gc] = v.x;
                es[(f * 4 + 1) * NC + gc] = v.y;
                es[(f * 4 + 2) * NC + gc] = v.z;
                es[(f * 4 + 3) * NC + gc] = v.w;
            }
            __syncthreads();

            // ---- 8x8 FMA micro-kernel ----
#pragma unroll 4
            for (int d = 0; d < KD; ++d) {
                float4 xa = *(const float4*)&xs[d * MP + ty * 8];
                float4 xb = *(const float4*)&xs[d * MP + ty * 8 + 4];
                int g = (tx ^ (d >> 2)) << 2;
                float4 ea = *(const float4*)&es[d * NC + g];
                float4 eb = *(const float4*)&es[d * NC + 128 + g];
                float xv[8] = {xa.x, xa.y, xa.z, xa.w, xb.x, xb.y, xb.z, xb.w};
                float ev[8] = {ea.x, ea.y, ea.z, ea.w, eb.x, eb.y, eb.z, eb.w};
#pragma unroll
                for (int i = 0; i < 8; ++i)
#pragma unroll
                    for (int j = 0; j < 8; ++j)
                        acc[i][j] = fmaf(xv[i], ev[j], acc[i][j]);
            }
        }

        // ---- fold into running argmin (candidates visited in ascending c) ----
#pragma unroll
        for (int j = 0; j < 8; ++j) {
            int c = k0 + ((j < 4) ? (tx * 4 + j) : (128 + tx * 4 + (j - 4)));
            float eec = ee[c];
#pragma unroll
            for (int i = 0; i < 8; ++i) {
                float dist = fmaf(-2.f, acc[i][j], eec);
                if (dist < best[i]) { best[i] = dist; bidx[i] = c; }
            }
        }
    }

    // ---- cross-lane argmin over 32 code lanes (same wave) ----
#pragma unroll
    for (int i = 0; i < 8; ++i) {
        float v = best[i];
        int   ix = bidx[i];
#pragma unroll
        for (int m = 16; m >= 1; m >>= 1) {
            float v2 = __shfl_xor(v, m);
            int   i2 = __shfl_xor(ix, m);
            if (v2 < v || (v2 == v && i2 < ix)) { v = v2; ix = i2; }
        }
        if (tx == 0) {
            if constexpr (KS == 1024) {
                sidx[ty * 8 + i] = ix;
            } else {
                pdist[split * Npts + pt0 + ty * 8 + i] = v;
                pidx [split * Npts + pt0 + ty * 8 + i] = ix;
            }
        }
    }

    if constexpr (KS == 1024) {
        __syncthreads();
        // ---- gather codes, write NCHW features, commitment loss ----
        float lsum = 0.f;
#pragma unroll 4
        for (int r = 0; r < D / 4; ++r) {
            int idx = r * 256 + tid;
            int p   = idx & 63;
            int dd  = idx >> 6;
            int k   = sidx[p];
            float e    = emb[(size_t)k * D + dd];
            float xv   = xbase[(size_t)dd * HW + p];
            float diff = e - xv;
            lsum = fmaf(diff, diff, lsum);
            out_feat[((size_t)b * D + dd) * HW + hw0 + p] = e;
        }
#pragma unroll
        for (int m = 32; m >= 1; m >>= 1) lsum += __shfl_xor(lsum, m);
        if ((tid & 63) == 0) atomicAdd(loss_out, lsum * loss_scale);
    }
}

// ---------------------------------------------------------------------------
// Fused kernel: all three levels in one grid (equal-MAC blocks).
// [0,960): L1 (D=128, full K)  [960,1920): L2 (D=256, K-split 4)
// [1920,5760): L0 (D=64, full K)
// ---------------------------------------------------------------------------
__global__ __launch_bounds__(256, 2)
void vq_main(const float* __restrict__ x0, const float* __restrict__ e0,
             const float* __restrict__ x1, const float* __restrict__ e1,
             const float* __restrict__ x2, const float* __restrict__ e2,
             const float* __restrict__ ee0, const float* __restrict__ ee1,
             const float* __restrict__ ee2,
             float* __restrict__ f0, float* __restrict__ f1, float* __restrict__ f2,
             float* __restrict__ pd2, int* __restrict__ pi2,
             float* __restrict__ loss)
{
    extern __shared__ char smem[];
    const int bid = blockIdx.x;
    if (bid < 960) {
        vq_block<128, 48 * 160, 1024>(x1, e1, ee1, f1, loss, 0.25f / 7864320.f,
                                      nullptr, nullptr, 61440, bid, 0, smem);
    } else if (bid < 1920) {
        int lb = bid - 960;
        vq_block<256, 24 * 80, 256>(x2, e2, ee2, nullptr, nullptr, 0.f,
                                    pd2, pi2, 15360, lb >> 2, lb & 3, smem);
    } else {
        vq_block<64, 96 * 320, 1024>(x0, e0, ee0, f0, loss, 0.25f / 15728640.f,
                                     nullptr, nullptr, 245760, bid - 1920, 0, smem);
    }
}

// ---------------------------------------------------------------------------
// Combine K-split partials for level 2 + epilogue.
// ---------------------------------------------------------------------------
template<int D, int HW, int NSPL>
__global__ void combine_kernel(const float* __restrict__ x, const float* __restrict__ emb,
                               const float* __restrict__ pdist, const int* __restrict__ pidx,
                               int Npts, float* __restrict__ out_feat,
                               float* __restrict__ loss_out, float loss_scale)
{
    __shared__ int sidx[64];
    const int tid = threadIdx.x;
    const int pt0 = blockIdx.x * 64;
    if (tid < 64) {
        int p = pt0 + tid;
        float bv = FLT_MAX; int bi = 0;
#pragma unroll
        for (int s = 0; s < NSPL; ++s) {            // ascending split = ascending codes
            float v = pdist[s * Npts + p];
            int  ix = pidx [s * Npts + p];
            if (v < bv) { bv = v; bi = ix; }        // strict < keeps lowest index
        }
        sidx[tid] = bi;
    }
    __syncthreads();
    const int b   = pt0 / HW;
    const int hw0 = pt0 % HW;
    const float* xbase = x + (size_t)b * D * HW + hw0;
    float lsum = 0.f;
#pragma unroll 4
    for (int r = 0; r < D / 4; ++r) {
        int idx = r * 256 + tid;
        int p   = idx & 63;
        int dd  = idx >> 6;
        int k   = sidx[p];
        float e    = emb[(size_t)k * D + dd];
        float xv   = xbase[(size_t)dd * HW + p];
        float diff = e - xv;
        lsum = fmaf(diff, diff, lsum);
        out_feat[((size_t)b * D + dd) * HW + hw0 + p] = e;
    }
#pragma unroll
    for (int m = 32; m >= 1; m >>= 1) lsum += __shfl_xor(lsum, m);
    if ((tid & 63) == 0) atomicAdd(loss_out, lsum * loss_scale);
}

// ---------------------------------------------------------------------------
extern "C" void kernel_launch(void* const* d_in, const int* in_sizes, int n_in,
                              void* d_out, int out_size, void* d_ws, size_t ws_size,
                              hipStream_t stream)
{
    const float* x0 = (const float*)d_in[0];
    const float* e0 = (const float*)d_in[1];
    const float* x1 = (const float*)d_in[2];
    const float* e1 = (const float*)d_in[3];
    const float* x2 = (const float*)d_in[4];
    const float* e2 = (const float*)d_in[5];

    float* out  = (float*)d_out;
    float* loss = out;
    float* f0   = out + 1;
    float* f1   = f0 + 15728640;   // 8*64*96*320
    float* f2   = f1 + 7864320;    // 8*128*48*160

    float* ee0 = (float*)d_ws;
    float* ee1 = ee0 + 1024;
    float* ee2 = ee1 + 1024;
    float* pd2 = ee2 + 1024;             // 4 * 15360 floats
    int*   pi2 = (int*)(pd2 + 4 * 15360);

    hipMemsetAsync(loss, 0, sizeof(float), stream);

    ee_kernel<64 ><<<256, 256, 0, stream>>>(e0, ee0);
    ee_kernel<128><<<256, 256, 0, stream>>>(e1, ee1);
    ee_kernel<256><<<256, 256, 0, stream>>>(e2, ee2);

    const int smem_bytes = (KD * MP + KD * NC) * 4 + MP * 4;   // 41216
    vq_main<<<5760, 256, smem_bytes, stream>>>(x0, e0, x1, e1, x2, e2,
                                               ee0, ee1, ee2,
                                               f0, f1, f2, pd2, pi2, loss);

    combine_kernel<256, 24 * 80, 4><<<240, 256, 0, stream>>>(
        x2, e2, pd2, pi2, 15360, f2, loss, 0.25f / 3932160.f);
}

// Round 3
// 877.278 us; speedup vs baseline: 1.4694x; 1.0892x over previous
//
#include <hip/hip_runtime.h>
#include <float.h>

typedef __bf16 bf16x8 __attribute__((ext_vector_type(8)));
typedef float  f32x16 __attribute__((ext_vector_type(16)));

// fp32 -> bf16 (RNE) as raw short
__device__ __forceinline__ short f2bf(float f) {
    unsigned u = __float_as_uint(f);
    unsigned r = (u + 0x7FFFu + ((u >> 16) & 1u)) >> 16;
    return (short)r;
}
__device__ __forceinline__ float bf2f(short s) {
    return __uint_as_float(((unsigned)(unsigned short)s) << 16);
}

// ---------------------------------------------------------------------------
// |e|^2 for all three codebooks. One wave per code, 4 codes/block.
// bid<256: L0; <512: L1; else L2.
// ---------------------------------------------------------------------------
__global__ void ee_all(const float* __restrict__ e0, const float* __restrict__ e1,
                       const float* __restrict__ e2, float* __restrict__ ee)
{
    int bid = blockIdx.x;
    const float* e; float* o; int D;
    if (bid < 256)      { e = e0; o = ee;        D = 64;  }
    else if (bid < 512) { e = e1; o = ee + 1024; D = 128; bid -= 256; }
    else                { e = e2; o = ee + 2048; D = 256; bid -= 512; }
    int k  = bid * 4 + (threadIdx.x >> 6);
    int ln = threadIdx.x & 63;
    float s = 0.f;
    for (int d = ln; d < D; d += 64) { float v = e[(size_t)k * D + d]; s = fmaf(v, v, s); }
#pragma unroll
    for (int m = 32; m >= 1; m >>= 1) s += __shfl_xor(s, m);
    if (ln == 0) o[k] = s;
}

// ---------------------------------------------------------------------------
// Main MFMA kernel. Block: 256 thr (4 waves), 128 points x (1024/NSPL) codes.
// LDS rows: [row][17 granules]; granule q = kstep*4 + half*2 + split (16B each).
// Frag reads: lane L: row r0+(L&31), granule stride 17 (odd) -> conflict-free.
// 3-term split-bf16: acc += xh*eh + xh*el + xl*eh.
// Writes per-point partials (m1, m2, i1) into the point's own feature planes
// (d-planes split*3 .. split*3+2) -- consumed by finalize before overwrite.
// ---------------------------------------------------------------------------
__shared__ __align__(16) short sm_main[34816];   // 68 KB: x 128x136, e 128x136

template<int D, int HW, int NSPL>
__device__ void vq_core(const float* __restrict__ x, const float* __restrict__ emb,
                        const float* __restrict__ ee, float* __restrict__ pslots,
                        int ptblk, int split)
{
    constexpr int CGS = (1024 / NSPL) / 128;
    constexpr int KCS = D / 64;
    short* xs = sm_main;            // 128 rows * 136 shorts
    short* es = sm_main + 17408;

    const int tid  = threadIdx.x;
    const int L    = tid & 63;
    const int wave = tid >> 6;
    const int half = L >> 5;

    const int pt0 = ptblk * 128;
    const int b   = pt0 / HW;
    const int hw0 = pt0 % HW;
    const float* xb = x + ((size_t)b * D) * HW + hw0;

    float m1[16], m2[16]; int i1[16];
#pragma unroll
    for (int r = 0; r < 16; ++r) { m1[r] = FLT_MAX; m2[r] = FLT_MAX; i1[r] = 0; }

    for (int cg = 0; cg < CGS; ++cg) {
        const int code0 = split * (1024 / NSPL) + cg * 128;
        f32x16 acc[4];
#pragma unroll
        for (int t = 0; t < 4; ++t)
#pragma unroll
            for (int j = 0; j < 16; ++j) acc[t][j] = 0.f;

        for (int kc = 0; kc < KCS; ++kc) {
            __syncthreads();
            // ---- stage x chunk (transpose + bf16 split), only when needed ----
            if (cg == 0 || KCS > 1) {
#pragma unroll
                for (int it = 0; it < 8; ++it) {
                    int pp = (it & 1) * 64 + (tid & 63);
                    int dq = (tid >> 6) + 4 * (it >> 1);
                    int d0 = dq * 4;
                    float v0 = xb[(size_t)(kc * 64 + d0 + 0) * HW + pp];
                    float v1 = xb[(size_t)(kc * 64 + d0 + 1) * HW + pp];
                    float v2 = xb[(size_t)(kc * 64 + d0 + 2) * HW + pp];
                    float v3 = xb[(size_t)(kc * 64 + d0 + 3) * HW + pp];
                    short h0 = f2bf(v0), h1 = f2bf(v1), h2 = f2bf(v2), h3 = f2bf(v3);
                    short l0 = f2bf(v0 - bf2f(h0)), l1 = f2bf(v1 - bf2f(h1));
                    short l2 = f2bf(v2 - bf2f(h2)), l3 = f2bf(v3 - bf2f(h3));
                    int q = (d0 >> 4) * 4 + ((d0 >> 3) & 1) * 2;
                    short* wp = xs + pp * 136 + q * 8 + (d0 & 7);
                    *(short4*)(wp)     = make_short4(h0, h1, h2, h3);
                    *(short4*)(wp + 8) = make_short4(l0, l1, l2, l3);
                }
            }
            // ---- stage e chunk (convert from fp32, d-fast: cheap) ----
#pragma unroll
            for (int it = 0; it < 16; ++it) {
                int flat = it * 256 + tid;
                int row = flat >> 5, dp = flat & 31, d0 = dp * 2;
                float2 v = *(const float2*)(emb + (size_t)(code0 + row) * D + kc * 64 + d0);
                short h0 = f2bf(v.x), h1 = f2bf(v.y);
                short l0 = f2bf(v.x - bf2f(h0)), l1 = f2bf(v.y - bf2f(h1));
                int q = (d0 >> 4) * 4 + ((d0 >> 3) & 1) * 2;
                short* wp = es + row * 136 + q * 8 + (d0 & 7);
                *(unsigned*)(wp)     = (unsigned short)h0 | ((unsigned)(unsigned short)h1 << 16);
                *(unsigned*)(wp + 8) = (unsigned short)l0 | ((unsigned)(unsigned short)l1 << 16);
            }
            __syncthreads();

            // ---- 4 ksteps x 4 code tiles x 3 MFMA terms ----
#pragma unroll
            for (int t4 = 0; t4 < 4; ++t4) {
                const short* ar = xs + (wave * 32 + (L & 31)) * 136 + (t4 * 4 + half * 2) * 8;
                bf16x8 ah = *(const bf16x8*)ar;
                bf16x8 al = *(const bf16x8*)(ar + 8);
#pragma unroll
                for (int t = 0; t < 4; ++t) {
                    const short* br = es + (t * 32 + (L & 31)) * 136 + (t4 * 4 + half * 2) * 8;
                    bf16x8 bh = *(const bf16x8*)br;
                    bf16x8 bl = *(const bf16x8*)(br + 8);
                    acc[t] = __builtin_amdgcn_mfma_f32_32x32x16_bf16(ah, bh, acc[t], 0, 0, 0);
                    acc[t] = __builtin_amdgcn_mfma_f32_32x32x16_bf16(ah, bl, acc[t], 0, 0, 0);
                    acc[t] = __builtin_amdgcn_mfma_f32_32x32x16_bf16(al, bh, acc[t], 0, 0, 0);
                }
            }
        }

        // ---- fold into running (m1, i1, m2) per (lane,reg) ----
#pragma unroll
        for (int t = 0; t < 4; ++t) {
            int c = code0 + t * 32 + (L & 31);
            float eec = ee[c];
#pragma unroll
            for (int r = 0; r < 16; ++r) {
                float dist = fmaf(-2.f, acc[t][r], eec);
                m2[r] = __builtin_amdgcn_fmed3f(dist, m1[r], m2[r]);
                bool lt = dist < m1[r];
                m1[r] = lt ? dist : m1[r];
                i1[r] = lt ? c : i1[r];
            }
        }
    }

    // ---- butterfly merge across the 32 lanes of each half ----
#pragma unroll
    for (int r = 0; r < 16; ++r) {
#pragma unroll
        for (int msk = 1; msk <= 16; msk <<= 1) {
            float om1 = __shfl_xor(m1[r], msk);
            int   oi  = __shfl_xor(i1[r], msk);
            float om2 = __shfl_xor(m2[r], msk);
            float mx  = fmaxf(m1[r], om1);
            m2[r] = fminf(mx, fminf(m2[r], om2));
            bool tk = (om1 < m1[r]) || (om1 == m1[r] && oi < i1[r]);
            m1[r] = tk ? om1 : m1[r];
            i1[r] = tk ? oi  : i1[r];
        }
    }
    // ---- write partials into this point's feature planes ----
#pragma unroll
    for (int r = 0; r < 16; ++r) {
        int row = (r & 3) + 8 * (r >> 2) + 4 * half;
        if ((L & 31) == row) {
            float* sl = pslots + ((size_t)(b * D) + split * 3) * HW + hw0 + wave * 32 + row;
            sl[0]          = m1[r];
            sl[(size_t)HW]     = m2[r];
            sl[(size_t)2 * HW] = __int_as_float(i1[r]);
        }
    }
}

__global__ __launch_bounds__(256, 2)
void vq_main(const float* __restrict__ x0, const float* __restrict__ e0,
             const float* __restrict__ x1, const float* __restrict__ e1,
             const float* __restrict__ x2, const float* __restrict__ e2,
             const float* __restrict__ ee,
             float* __restrict__ f0, float* __restrict__ f1, float* __restrict__ f2)
{
    int bid = blockIdx.x;
    if (bid < 480) {
        vq_core<128, 7680, 1>(x1, e1, ee + 1024, f1, bid, 0);
    } else if (bid < 720) {
        int lb = bid - 480;
        vq_core<256, 1920, 2>(x2, e2, ee + 2048, f2, lb >> 1, lb & 1);
    } else {
        vq_core<64, 30720, 1>(x0, e0, ee, f0, bid - 720, 0);
    }
}

// ---------------------------------------------------------------------------
// Finalize: merge split partials, margin-certify, brute-force rare near-ties
// in exact fp32, then gather codes / write features / commitment loss.
// 64 points per 256-thread block.
// ---------------------------------------------------------------------------
template<int D, int HW, int NSPL>
__device__ void fin_core(const float* __restrict__ x, const float* __restrict__ emb,
                         const float* __restrict__ ee, float* __restrict__ feat,
                         float margin, float lscale, float* __restrict__ loss, int ptblk)
{
    __shared__ int sidx[64];
    __shared__ int flags[64];
    __shared__ float sx[256];
    __shared__ unsigned long long red;

    const int tid = threadIdx.x;
    const int pt0 = ptblk * 64;
    const int b   = pt0 / HW;
    const int hw0 = pt0 % HW;

    if (tid < 64) {
        const float* sl = feat + (size_t)(b * D) * HW + hw0 + tid;
        float bm1 = FLT_MAX, bm2 = FLT_MAX; int bi = 0;
#pragma unroll
        for (int s = 0; s < NSPL; ++s) {
            float am1 = sl[(size_t)(s * 3 + 0) * HW];
            float am2 = sl[(size_t)(s * 3 + 1) * HW];
            int   ai  = __float_as_int(sl[(size_t)(s * 3 + 2) * HW]);
            float mx  = fmaxf(bm1, am1);
            bm2 = fminf(mx, fminf(bm2, am2));
            bool tk = (am1 < bm1) || (am1 == bm1 && ai < bi);
            bm1 = tk ? am1 : bm1;
            bi  = tk ? ai  : bi;
        }
        sidx[tid]  = bi;
        flags[tid] = (bm2 - bm1 <= margin) ? 1 : 0;
    }
    __syncthreads();

    // rare exact re-resolve
    for (int q = 0; q < 64; ++q) {
        if (flags[q]) {
            int phw = hw0 + q;
            for (int d = tid; d < D; d += 256) sx[d] = x[((size_t)b * D + d) * HW + phw];
            if (tid == 0) red = ~0ull;
            __syncthreads();
#pragma unroll
            for (int j = 0; j < 4; ++j) {
                int c = j * 256 + tid;
                float s = 0.f;
                for (int d = 0; d < D; ++d) s = fmaf(sx[d], emb[(size_t)c * D + d], s);
                float dist = fmaf(-2.f, s, ee[c]);
                unsigned u = __float_as_uint(dist);
                u = (u >> 31) ? ~u : (u | 0x80000000u);
                unsigned long long pk = ((unsigned long long)u << 32) | (unsigned)c;
                atomicMin(&red, pk);
            }
            __syncthreads();
            if (tid == 0) sidx[q] = (int)(red & 0xFFFFFFFFull);
            __syncthreads();
        }
    }

    // epilogue: gather, write NCHW features (overwrites partial slots), loss
    float lsum = 0.f;
#pragma unroll 4
    for (int r = 0; r < D / 4; ++r) {
        int idx = r * 256 + tid;
        int p   = idx & 63;
        int dd  = idx >> 6;
        int k   = sidx[p];
        float e    = emb[(size_t)k * D + dd];
        float xv   = x[((size_t)b * D + dd) * HW + hw0 + p];
        float diff = e - xv;
        lsum = fmaf(diff, diff, lsum);
        feat[((size_t)b * D + dd) * HW + hw0 + p] = e;
    }
#pragma unroll
    for (int m = 32; m >= 1; m >>= 1) lsum += __shfl_xor(lsum, m);
    if ((tid & 63) == 0) atomicAdd(loss, lsum * lscale);
}

__global__ void vq_finalize(const float* __restrict__ x0, const float* __restrict__ e0,
                            const float* __restrict__ x1, const float* __restrict__ e1,
                            const float* __restrict__ x2, const float* __restrict__ e2,
                            const float* __restrict__ ee,
                            float* __restrict__ f0, float* __restrict__ f1,
                            float* __restrict__ f2, float* __restrict__ loss)
{
    int bid = blockIdx.x;
    if (bid < 3840) {
        fin_core<64, 30720, 1>(x0, e0, ee, f0, 4e-3f, 0.25f / 15728640.f, loss, bid);
    } else if (bid < 4800) {
        fin_core<128, 7680, 1>(x1, e1, ee + 1024, f1, 5e-3f, 0.25f / 7864320.f, loss, bid - 3840);
    } else {
        fin_core<256, 1920, 2>(x2, e2, ee + 2048, f2, 8e-3f, 0.25f / 3932160.f, loss, bid - 4800);
    }
}

// ---------------------------------------------------------------------------
extern "C" void kernel_launch(void* const* d_in, const int* in_sizes, int n_in,
                              void* d_out, int out_size, void* d_ws, size_t ws_size,
                              hipStream_t stream)
{
    const float* x0 = (const float*)d_in[0];
    const float* e0 = (const float*)d_in[1];
    const float* x1 = (const float*)d_in[2];
    const float* e1 = (const float*)d_in[3];
    const float* x2 = (const float*)d_in[4];
    const float* e2 = (const float*)d_in[5];

    float* out  = (float*)d_out;
    float* loss = out;
    float* f0   = out + 1;
    float* f1   = f0 + 15728640;   // 8*64*96*320
    float* f2   = f1 + 7864320;    // 8*128*48*160

    float* ee = (float*)d_ws;      // 3*1024 floats

    hipMemsetAsync(loss, 0, sizeof(float), stream);

    ee_all<<<768, 256, 0, stream>>>(e0, e1, e2, ee);

    vq_main<<<2640, 256, 0, stream>>>(x0, e0, x1, e1, x2, e2, ee, f0, f1, f2);

    vq_finalize<<<5040, 256, 0, stream>>>(x0, e0, x1, e1, x2, e2, ee, f0, f1, f2, loss);
}

// Round 4
// 526.650 us; speedup vs baseline: 2.4477x; 1.6658x over previous
//
#include <hip/hip_runtime.h>
#include <float.h>

typedef __bf16 bf16x8 __attribute__((ext_vector_type(8)));
typedef float  f32x16 __attribute__((ext_vector_type(16)));

// ws byte layout
#define WS_EE    0                           // 3*1024 floats
#define WS_SLOT  12288                       // 128 float loss slots
#define WS_IMG0  16384                       // emb split images
#define WS_IMG1  (WS_IMG0 + 4096 * 64)
#define WS_IMG2  (WS_IMG1 + 4096 * 128)

__device__ __forceinline__ short f2bf(float f) {
    unsigned u = __float_as_uint(f);
    unsigned r = (u + 0x7FFFu + ((u >> 16) & 1u)) >> 16;
    return (short)r;
}
__device__ __forceinline__ float bf2f(short s) {
    return __uint_as_float(((unsigned)(unsigned short)s) << 16);
}
__device__ __forceinline__ unsigned pk2(short a, short b) {
    return (unsigned)(unsigned short)a | ((unsigned)(unsigned short)b << 16);
}

// ---------------------------------------------------------------------------
// |e|^2 for all three codebooks.
// ---------------------------------------------------------------------------
__global__ void ee_all(const float* __restrict__ e0, const float* __restrict__ e1,
                       const float* __restrict__ e2, float* __restrict__ ee)
{
    int bid = blockIdx.x;
    const float* e; float* o; int D;
    if (bid < 256)      { e = e0; o = ee;        D = 64;  }
    else if (bid < 512) { e = e1; o = ee + 1024; D = 128; bid -= 256; }
    else                { e = e2; o = ee + 2048; D = 256; bid -= 512; }
    int k  = bid * 4 + (threadIdx.x >> 6);
    int ln = threadIdx.x & 63;
    float s = 0.f;
    for (int d = ln; d < D; d += 64) { float v = e[(size_t)k * D + d]; s = fmaf(v, v, s); }
#pragma unroll
    for (int m = 32; m >= 1; m >>= 1) s += __shfl_xor(s, m);
    if (ln == 0) o[k] = s;
}

// ---------------------------------------------------------------------------
// Pre-split emb into hi/lo bf16 fragment-layout images.
// Image per level: [ct 0..7][kc 0..KCS-1] regions of 128 rows x 256 B.
// Row r (code within tile), granule q = t4*4 + half*2 + hilo stored at
// physical granule q ^ (r & 7)  (bank-optimal for b128 frag reads).
// ---------------------------------------------------------------------------
__global__ void prep_emb(const float* __restrict__ e0, const float* __restrict__ e1,
                         const float* __restrict__ e2, char* __restrict__ ws)
{
    int flat = blockIdx.x * 256 + threadIdx.x;       // [0, 57344)
    const float* emb; char* img; int D, id;
    if (flat < 8192)       { emb = e0; img = ws + WS_IMG0; D = 64;  id = flat; }
    else if (flat < 24576) { emb = e1; img = ws + WS_IMG1; D = 128; id = flat - 8192; }
    else                   { emb = e2; img = ws + WS_IMG2; D = 256; id = flat - 24576; }
    int chunks = D >> 3;
    int c  = id / chunks;
    int ch = id - c * chunks;
    int d0 = ch * 8;
    int kc = d0 >> 6;
    int dd = d0 & 63;
    int q  = ((dd >> 4) << 2) + (((dd >> 3) & 1) << 1);
    int r  = c & 127;
    int ct = c >> 7;
    const float* s = emb + (size_t)c * D + d0;
    unsigned hw[4], lw[4];
#pragma unroll
    for (int j = 0; j < 4; ++j) {
        float va = s[2 * j], vb = s[2 * j + 1];
        short ha = f2bf(va), hb = f2bf(vb);
        short la = f2bf(va - bf2f(ha)), lb = f2bf(vb - bf2f(hb));
        hw[j] = pk2(ha, hb);
        lw[j] = pk2(la, lb);
    }
    char* base = img + ((size_t)(ct * (D >> 6) + kc)) * 32768 + r * 256;
    *(uint4*)(base + ((q       ^ (r & 7)) << 4)) = make_uint4(hw[0], hw[1], hw[2], hw[3]);
    *(uint4*)(base + (((q + 1) ^ (r & 7)) << 4)) = make_uint4(lw[0], lw[1], lw[2], lw[3]);
}

// ---------------------------------------------------------------------------
// Main fused kernel (file-scope LDS shared across template instantiations)
// ---------------------------------------------------------------------------
__shared__ __align__(16) short g_x[16384];   // x tile: [kc][pt row][16 granules]
__shared__ __align__(16) short g_e[16384];   // e tile: 128 rows x 16 granules
__shared__ float g_m1[128];
__shared__ float g_m2[128];
__shared__ int   g_i1[128];
__shared__ int   g_sidx[128];
__shared__ float g_d1[128];
__shared__ int   g_flag[130];                // [0]=count, then list
__shared__ unsigned long long g_red;
__shared__ float g_part[4];

template<int D, int HW, int PTS>
__device__ void vq_core2(const float* __restrict__ x, const float* __restrict__ emb,
                         const float* __restrict__ eesq, const char* __restrict__ eimg,
                         float* __restrict__ feat, float* __restrict__ slots,
                         float lscale, float margin, int ptblk)
{
    constexpr int KCS  = D / 64;
    constexpr int ROWG = PTS / 32;   // row groups == t-tiles per wave
    constexpr int TPW  = ROWG;
    constexpr int W    = 4 / ROWG;   // code groups per point

    const int tid  = threadIdx.x;
    const int L    = tid & 63;
    const int wave = tid >> 6;
    const int col  = L & 31;
    const int half = L >> 5;
    const int rowg = wave % ROWG;
    const int cgrp = wave / ROWG;

    const int pt0 = ptblk * PTS;     // HW % PTS == 0 -> tile within one batch b
    const int b   = pt0 / HW;
    const int hw0 = pt0 % HW;
    const float* xb = x + (size_t)b * D * HW + hw0;

    // ---- stage x once (split bf16 + swizzle), accumulate |x|^2 ----
    float ssq = 0.f;
#pragma unroll
    for (int it = 0; it < 4; ++it) {
        int flat = it * 256 + tid;           // [0, PTS*D/8)
        int pt   = flat % PTS;
        int dch  = flat / PTS;
        int d0   = dch * 8;
        int kc   = d0 >> 6;
        int dd   = d0 & 63;
        int q    = ((dd >> 4) << 2) + (((dd >> 3) & 1) << 1);
        unsigned hw_[4], lw_[4];
#pragma unroll
        for (int j = 0; j < 4; ++j) {
            float va = xb[(size_t)(d0 + 2 * j)     * HW + pt];
            float vb = xb[(size_t)(d0 + 2 * j + 1) * HW + pt];
            ssq = fmaf(va, va, ssq);
            ssq = fmaf(vb, vb, ssq);
            short ha = f2bf(va), hb = f2bf(vb);
            short la = f2bf(va - bf2f(ha)), lb = f2bf(vb - bf2f(hb));
            hw_[j] = pk2(ha, hb);
            lw_[j] = pk2(la, lb);
        }
        short* row = g_x + kc * (PTS * 128) + pt * 128;
        *(uint4*)(row + (((q    ) ^ (pt & 7)) << 3)) = make_uint4(hw_[0], hw_[1], hw_[2], hw_[3]);
        *(uint4*)(row + (((q + 1) ^ (pt & 7)) << 3)) = make_uint4(lw_[0], lw_[1], lw_[2], lw_[3]);
    }
    if (tid == 0) g_flag[0] = 0;

    float m1[16], m2[16]; int i1[16];
#pragma unroll
    for (int r = 0; r < 16; ++r) { m1[r] = FLT_MAX; m2[r] = FLT_MAX; i1[r] = 0; }

    const int arow = rowg * 32 + col;
    const short* xrow0 = g_x + arow * 128;

    for (int cg = 0; cg < 8; ++cg) {
        f32x16 acc[TPW];
#pragma unroll
        for (int t = 0; t < TPW; ++t)
#pragma unroll
            for (int j = 0; j < 16; ++j) acc[t][j] = 0.f;

        for (int kc = 0; kc < KCS; ++kc) {
            __syncthreads();
            // ---- stage e tile: pure 16B copies from pre-split image ----
            const uint4* esrc = (const uint4*)(eimg + (size_t)(cg * KCS + kc) * 32768);
            uint4* edst = (uint4*)g_e;
#pragma unroll
            for (int it = 0; it < 8; ++it) {
                int g = it * 256 + tid;
                edst[g] = esrc[g];
            }
            __syncthreads();

            const short* xck = xrow0 + kc * (PTS * 128);
#pragma unroll
            for (int t4 = 0; t4 < 4; ++t4) {
                int qh = t4 * 4 + half * 2;
                bf16x8 ah = *(const bf16x8*)(xck + (((qh    ) ^ (arow & 7)) << 3));
                bf16x8 al = *(const bf16x8*)(xck + (((qh + 1) ^ (arow & 7)) << 3));
#pragma unroll
                for (int t = 0; t < TPW; ++t) {
                    int brow = (cgrp * TPW + t) * 32 + col;
                    const short* br = g_e + brow * 128;
                    bf16x8 bh = *(const bf16x8*)(br + (((qh    ) ^ (brow & 7)) << 3));
                    bf16x8 bl = *(const bf16x8*)(br + (((qh + 1) ^ (brow & 7)) << 3));
                    acc[t] = __builtin_amdgcn_mfma_f32_32x32x16_bf16(ah, bh, acc[t], 0, 0, 0);
                    acc[t] = __builtin_amdgcn_mfma_f32_32x32x16_bf16(ah, bl, acc[t], 0, 0, 0);
                    acc[t] = __builtin_amdgcn_mfma_f32_32x32x16_bf16(al, bh, acc[t], 0, 0, 0);
                }
            }
        }

        // ---- fold codes of this group into (m1, i1, m2) ----
#pragma unroll
        for (int t = 0; t < TPW; ++t) {
            int c = cg * 128 + (cgrp * TPW + t) * 32 + col;
            float eec = eesq[c];
#pragma unroll
            for (int r = 0; r < 16; ++r) {
                float dist = fmaf(-2.f, acc[t][r], eec);
                m2[r] = __builtin_amdgcn_fmed3f(dist, m1[r], m2[r]);
                bool lt = dist < m1[r];
                m1[r] = lt ? dist : m1[r];
                i1[r] = lt ? c : i1[r];
            }
        }
    }

    // ---- butterfly across the 32 lanes of each half ----
#pragma unroll
    for (int r = 0; r < 16; ++r) {
#pragma unroll
        for (int msk = 1; msk <= 16; msk <<= 1) {
            float om1 = __shfl_xor(m1[r], msk);
            int   oi  = __shfl_xor(i1[r], msk);
            float om2 = __shfl_xor(m2[r], msk);
            float mx  = fmaxf(m1[r], om1);
            m2[r] = fminf(mx, fminf(m2[r], om2));
            bool tk = (om1 < m1[r]) || (om1 == m1[r] && oi < i1[r]);
            m1[r] = tk ? om1 : m1[r];
            i1[r] = tk ? oi  : i1[r];
        }
    }
    // ---- publish per (point, code-group) ----
#pragma unroll
    for (int r = 0; r < 16; ++r) {
        int r16 = (r & 3) + 8 * (r >> 2) + 4 * half;
        if (col == r16) {
            int p = rowg * 32 + r16;
            g_m1[p * W + cgrp] = m1[r];
            g_m2[p * W + cgrp] = m2[r];
            g_i1[p * W + cgrp] = i1[r];
        }
    }
    __syncthreads();

    // ---- merge code groups, margin-certify ----
    if (tid < PTS) {
        float bm1 = FLT_MAX, bm2 = FLT_MAX; int bi = 0x7FFFFFFF;
#pragma unroll
        for (int s = 0; s < W; ++s) {
            float am1 = g_m1[tid * W + s];
            float am2 = g_m2[tid * W + s];
            int   ai  = g_i1[tid * W + s];
            float mx  = fmaxf(bm1, am1);
            bm2 = fminf(mx, fminf(bm2, am2));
            bool tk = (am1 < bm1) || (am1 == bm1 && ai < bi);
            bm1 = tk ? am1 : bm1;
            bi  = tk ? ai  : bi;
        }
        g_sidx[tid] = bi;
        g_d1[tid]   = bm1;
        if (bm2 - bm1 <= margin) {
            int pos = atomicAdd(&g_flag[0], 1);
            g_flag[1 + pos] = tid;
        }
    }
    __syncthreads();

    // ---- rare exact fp32 re-resolve for near-ties ----
    int nf = g_flag[0];
    float* sx = (float*)g_e;    // e tile no longer needed
    for (int i = 0; i < nf; ++i) {
        int p   = g_flag[1 + i];
        int phw = hw0 + p;
        for (int d = tid; d < D; d += 256) sx[d] = x[((size_t)b * D + d) * HW + phw];
        if (tid == 0) g_red = ~0ull;
        __syncthreads();
#pragma unroll
        for (int j = 0; j < 4; ++j) {
            int c = j * 256 + tid;
            float s = 0.f;
#pragma unroll 4
            for (int d = 0; d < D; ++d) s = fmaf(sx[d], emb[(size_t)c * D + d], s);
            float dist = fmaf(-2.f, s, eesq[c]);
            unsigned u = __float_as_uint(dist);
            u = (u >> 31) ? ~u : (u | 0x80000000u);
            unsigned long long pkv = ((unsigned long long)u << 32) | (unsigned)c;
            atomicMin(&g_red, pkv);
        }
        __syncthreads();
        if (tid == 0) {
            unsigned u = (unsigned)(g_red >> 32);
            unsigned orig = (u & 0x80000000u) ? (u ^ 0x80000000u) : ~u;
            g_sidx[p] = (int)(g_red & 0xFFFFFFFFu);
            g_d1[p]   = __uint_as_float(orig);
        }
        __syncthreads();
    }

    // ---- epilogue: gather chosen codes, write NCHW features ----
#pragma unroll 4
    for (int it = 0; it < (PTS * D) / 256; ++it) {
        int flat = it * 256 + tid;
        int p  = flat % PTS;
        int dd = flat / PTS;
        int k  = g_sidx[p];
        feat[((size_t)b * D + dd) * HW + hw0 + p] = emb[(size_t)k * D + dd];
    }

    // ---- loss: sum(dist_chosen) + sum(|x|^2), one atomic into spread slots ----
    float lsum = ssq;
    if (tid < PTS) lsum += g_d1[tid];
#pragma unroll
    for (int m = 32; m >= 1; m >>= 1) lsum += __shfl_xor(lsum, m);
    if (L == 0) g_part[wave] = lsum;
    __syncthreads();
    if (tid == 0) {
        float tot = (g_part[0] + g_part[1]) + (g_part[2] + g_part[3]);
        atomicAdd(&slots[blockIdx.x & 127], tot * lscale);
    }
}

__global__ __launch_bounds__(256, 2)
void vq_main2(const float* __restrict__ x0, const float* __restrict__ e0,
              const float* __restrict__ x1, const float* __restrict__ e1,
              const float* __restrict__ x2, const float* __restrict__ e2,
              char* __restrict__ ws,
              float* __restrict__ f0, float* __restrict__ f1, float* __restrict__ f2)
{
    const float* ee = (const float*)ws;
    float* slots = (float*)(ws + WS_SLOT);
    int bid = blockIdx.x;
    if (bid < 480) {
        vq_core2<256, 1920, 32>(x2, e2, ee + 2048, ws + WS_IMG2, f2, slots,
                                0.25f / 3932160.f, 8e-3f, bid);
    } else if (bid < 1440) {
        vq_core2<128, 7680, 64>(x1, e1, ee + 1024, ws + WS_IMG1, f1, slots,
                                0.25f / 7864320.f, 5e-3f, bid - 480);
    } else {
        vq_core2<64, 30720, 128>(x0, e0, ee, ws + WS_IMG0, f0, slots,
                                 0.25f / 15728640.f, 4e-3f, bid - 1440);
    }
}

// ---------------------------------------------------------------------------
__global__ void loss_finish(const float* __restrict__ slots, float* __restrict__ out)
{
    int t = threadIdx.x;     // 128
    float v = slots[t];
#pragma unroll
    for (int m = 32; m >= 1; m >>= 1) v += __shfl_xor(v, m);
    __shared__ float p2[2];
    if ((t & 63) == 0) p2[t >> 6] = v;
    __syncthreads();
    if (t == 0) out[0] = p2[0] + p2[1];
}

// ---------------------------------------------------------------------------
extern "C" void kernel_launch(void* const* d_in, const int* in_sizes, int n_in,
                              void* d_out, int out_size, void* d_ws, size_t ws_size,
                              hipStream_t stream)
{
    const float* x0 = (const float*)d_in[0];
    const float* e0 = (const float*)d_in[1];
    const float* x1 = (const float*)d_in[2];
    const float* e1 = (const float*)d_in[3];
    const float* x2 = (const float*)d_in[4];
    const float* e2 = (const float*)d_in[5];

    float* out  = (float*)d_out;
    float* f0   = out + 1;
    float* f1   = f0 + 15728640;   // 8*64*96*320
    float* f2   = f1 + 7864320;    // 8*128*48*160

    char* ws = (char*)d_ws;
    float* eef   = (float*)ws;
    float* slots = (float*)(ws + WS_SLOT);

    hipMemsetAsync(slots, 0, 128 * sizeof(float), stream);

    ee_all<<<768, 256, 0, stream>>>(e0, e1, e2, eef);
    prep_emb<<<224, 256, 0, stream>>>(e0, e1, e2, ws);

    vq_main2<<<3360, 256, 0, stream>>>(x0, e0, x1, e1, x2, e2, ws, f0, f1, f2);

    loss_finish<<<1, 128, 0, stream>>>(slots, out);
}